// Round 2
// baseline (1890.199 us; speedup 1.0000x reference)
//
#include <hip/hip_runtime.h>
#include <math.h>

#define SEQ     2048
#define NB      2
#define NHEADS  32
#define DHEAD   128
#define HID     4096
#define NQKV    12288
#define T_TOKENS (NB*SEQ)

typedef _Float16 half8 __attribute__((ext_vector_type(8)));
typedef float v4f __attribute__((ext_vector_type(4)));

__device__ __forceinline__ void gload_lds16(const void* g, void* l) {
    __builtin_amdgcn_global_load_lds(
        (__attribute__((address_space(1))) void*)(void*)(g),
        (__attribute__((address_space(3))) void*)(unsigned)(unsigned long long)(l),
        16, 0, 0);
}

__device__ __forceinline__ v4f mfma16(half8 a, half8 b, v4f c) {
    return __builtin_amdgcn_mfma_f32_16x16x32_f16(a, b, c, 0, 0, 0);
}

// ---------------- routing ----------------
__global__ void route_kernel(const int* __restrict__ tt, int* counts, int* idx) {
    int t = blockIdx.x * blockDim.x + threadIdx.x;
    if (t >= T_TOKENS) return;
    int s = t & (SEQ - 1);
    bool vm = (s < SEQ - 1) && (tt[t] == 1) && (tt[t + 1] == 1);
    int e = vm ? 0 : 1;
    int p = atomicAdd(&counts[e], 1);
    idx[e * T_TOKENS + p] = t;
}

// ---------------- RoPE cos/sin table (accurate, once per call) ----------------
// tab[tok*64 + j] = (cos, sin) of pos[tok] * 10000^(-j/64)
__global__ void rope_table_kernel(const int* __restrict__ pos_ids, float2* __restrict__ tab) {
    int i = blockIdx.x * blockDim.x + threadIdx.x;
    if (i >= T_TOKENS * 64) return;
    int tok = i >> 6, j = i & 63;
    float invf = (float)pow(10000.0, -(double)j * (1.0 / 64.0));
    float ang = (float)pos_ids[tok] * invf;   // fp32, matches reference emb
    double ds, dc;
    sincos((double)ang, &ds, &dc);            // exact reduction of the fp32 value
    tab[i] = make_float2((float)dc, (float)ds);
}

// ---------------- fp32 -> fp16 ----------------
__global__ void cvt_f32_f16(const float* __restrict__ src, _Float16* __restrict__ dst, int n4) {
    int i = blockIdx.x * blockDim.x + threadIdx.x;
    if (i >= n4) return;
    float4 v = ((const float4*)src)[i];
    union { _Float16 h[4]; uint2 u; } p;
    p.h[0] = (_Float16)v.x; p.h[1] = (_Float16)v.y;
    p.h[2] = (_Float16)v.z; p.h[3] = (_Float16)v.w;
    ((uint2*)dst)[i] = p.u;
}

// ---------------- W [K][N] f32 -> WT [N][K] f16 ----------------
__global__ void transpose_cvt(const float* __restrict__ W, _Float16* __restrict__ WT,
                              int K, int N) {
    __shared__ _Float16 t[64][72];
    const int n0 = blockIdx.x * 64, k0 = blockIdx.y * 64;
    const int cr = threadIdx.x & 15, rr = threadIdx.x >> 4;
#pragma unroll
    for (int it = 0; it < 4; ++it) {
        int r = rr + it * 16;
        float4 v = *(const float4*)&W[(size_t)(k0 + r) * N + n0 + cr * 4];
        t[cr*4+0][r] = (_Float16)v.x; t[cr*4+1][r] = (_Float16)v.y;
        t[cr*4+2][r] = (_Float16)v.z; t[cr*4+3][r] = (_Float16)v.w;
    }
    __syncthreads();
#pragma unroll
    for (int it = 0; it < 4; ++it) {
        int r = rr + it * 16;
        union { _Float16 h[4]; uint2 u; } p;
#pragma unroll
        for (int j = 0; j < 4; ++j) p.h[j] = t[r][cr*4+j];
        *(uint2*)&WT[(size_t)(n0 + r) * K + k0 + cr * 4] = p.u;
    }
}

// ---------------- V [b,s,h,d] -> VT [bh][d][s] ----------------
__global__ void transpose_v(const _Float16* __restrict__ vin, _Float16* __restrict__ vout) {
    __shared__ _Float16 t[64][72];
    const int s0 = blockIdx.x * 64;
    const int d0 = blockIdx.y * 64;
    const int bh = blockIdx.z;
    const int b = bh >> 5, h = bh & 31;
    const int cr = threadIdx.x & 15, rr = threadIdx.x >> 4;
#pragma unroll
    for (int it = 0; it < 4; ++it) {
        int sl = rr + it * 16;
        union { _Float16 h4[4]; uint2 u; } p;
        p.u = *(const uint2*)&vin[(size_t)(b * SEQ + s0 + sl) * HID + h * DHEAD + d0 + cr * 4];
#pragma unroll
        for (int j = 0; j < 4; ++j) t[cr*4+j][sl] = p.h4[j];
    }
    __syncthreads();
#pragma unroll
    for (int it = 0; it < 4; ++it) {
        int dl = rr + it * 16;
        union { _Float16 h4[4]; uint2 u; } p;
#pragma unroll
        for (int j = 0; j < 4; ++j) p.h4[j] = t[dl][cr*4+j];
        *(uint2*)&vout[((size_t)bh * DHEAD + d0 + dl) * SEQ + s0 + cr * 4] = p.u;
    }
}

// ---------------- gathered-row expert GEMM ----------------
// MODE 0: qkv + fused RoPE scatter.  MODE 1: dense -> fp32 out.
// A [T][4096] f16, BT [N][4096] f16. Tile 128x128, BK=32, 4 waves stacked in M.
template <int MODE>
__global__ __launch_bounds__(256, 2)
void gemm_expert(const _Float16* __restrict__ A,
                 const _Float16* __restrict__ BT0,
                 const _Float16* __restrict__ BT1,
                 const int* __restrict__ counts,
                 const int* __restrict__ idx_all,
                 const float2* __restrict__ rope,
                 _Float16* __restrict__ qbuf,
                 _Float16* __restrict__ kbuf,
                 _Float16* __restrict__ vbuf,
                 float* __restrict__ out) {
    const int e = blockIdx.z;
    const int count = counts[e];
    const int rt = blockIdx.y;
    if (rt * 128 >= count) return;
    const int ct = blockIdx.x;
    const int* idx = idx_all + e * T_TOKENS;
    const _Float16* BT = e ? BT1 : BT0;

    __shared__ _Float16 sA[128 * 32];
    __shared__ _Float16 sB[128 * 32];

    const int tid = threadIdx.x;
    const int w = tid >> 6, lane = tid & 63;
    const int col = lane & 15, quad = lane >> 4;

    // staging rows: 2 segments of 16 rows per wave (A and B use same pattern)
    const int r0 = (w * 2 + 0) * 16 + (lane >> 2);
    const int r1 = (w * 2 + 1) * 16 + (lane >> 2);
    int g0 = rt * 128 + r0; if (g0 > count - 1) g0 = count - 1;
    int g1 = rt * 128 + r1; if (g1 > count - 1) g1 = count - 1;
    const int tok0 = idx[g0], tok1 = idx[g1];
    const _Float16* ag0 = A + (size_t)tok0 * HID + (lane & 3) * 8;
    const _Float16* ag1 = A + (size_t)tok1 * HID + (lane & 3) * 8;
    const _Float16* bg0 = BT + (size_t)(ct * 128 + r0) * HID + (lane & 3) * 8;
    const _Float16* bg1 = BT + (size_t)(ct * 128 + r1) * HID + (lane & 3) * 8;
    _Float16* sa0 = &sA[(w * 2 + 0) * 512];
    _Float16* sa1 = &sA[(w * 2 + 1) * 512];
    _Float16* sb0 = &sB[(w * 2 + 0) * 512];
    _Float16* sb1 = &sB[(w * 2 + 1) * 512];

    v4f acc[2][8];
#pragma unroll
    for (int i = 0; i < 2; ++i)
#pragma unroll
        for (int j = 0; j < 8; ++j) { v4f z = {0.f, 0.f, 0.f, 0.f}; acc[i][j] = z; }

    const int am0 = (w * 32 + col) * 32 + quad * 8;
    const int am1 = am0 + 16 * 32;

    for (int kt = 0; kt < HID / 32; ++kt) {
        __syncthreads();
        gload_lds16(ag0, sa0); gload_lds16(ag1, sa1);
        gload_lds16(bg0, sb0); gload_lds16(bg1, sb1);
        ag0 += 32; ag1 += 32; bg0 += 32; bg1 += 32;
        __syncthreads();
        half8 a0 = *(const half8*)&sA[am0];
        half8 a1 = *(const half8*)&sA[am1];
#pragma unroll
        for (int nt = 0; nt < 8; ++nt) {
            half8 b = *(const half8*)&sB[(nt * 16 + col) * 32 + quad * 8];
            acc[0][nt] = mfma16(a0, b, acc[0][nt]);
            acc[1][nt] = mfma16(a1, b, acc[1][nt]);
        }
    }

    const int n0 = ct * 128;
    if (MODE == 1) {
#pragma unroll
        for (int mt = 0; mt < 2; ++mt)
#pragma unroll
            for (int r = 0; r < 4; ++r) {
                int rg = rt * 128 + w * 32 + mt * 16 + quad * 4 + r;
                if (rg >= count) continue;
                int tok = idx[rg];
                float* dst = out + (size_t)tok * HID + n0;
#pragma unroll
                for (int nt = 0; nt < 8; ++nt) dst[nt * 16 + col] = acc[mt][nt][r];
            }
    } else {
        const int sec = n0 >> 12;          // 0=q 1=k 2=v
        const int h = (n0 >> 7) & 31;
#pragma unroll
        for (int mt = 0; mt < 2; ++mt)
#pragma unroll
            for (int r = 0; r < 4; ++r) {
                int rg = rt * 128 + w * 32 + mt * 16 + quad * 4 + r;
                if (rg >= count) continue;
                int tok = idx[rg];
                int b = tok >> 11, s = tok & (SEQ - 1);
                if (sec == 2) {
                    _Float16* dst = vbuf + (size_t)tok * HID + h * DHEAD;
#pragma unroll
                    for (int nt = 0; nt < 8; ++nt) dst[nt * 16 + col] = (_Float16)acc[mt][nt][r];
                } else {
                    _Float16* dst = (sec ? kbuf : qbuf) + ((size_t)(b * NHEADS + h) * SEQ + s) * DHEAD;
                    const float2* tp = rope + (size_t)tok * 64;
#pragma unroll
                    for (int nt = 0; nt < 4; ++nt) {
                        int d = nt * 16 + col;
                        float2 cs = tp[d];
                        float x = acc[mt][nt][r], y = acc[mt][nt + 4][r];
                        dst[d]      = (_Float16)(x * cs.x - y * cs.y);
                        dst[d + 64] = (_Float16)(y * cs.x + x * cs.y);
                    }
                }
            }
    }
}

// ---------------- flash attention ----------------
// q,k: [bh][s][d] f16 (rope'd, q pre-scaled here), vt: [bh][d][s] f16, ctx: [b,s,h,d] f16
__global__ __launch_bounds__(256, 2)
void attn_kernel(const _Float16* __restrict__ qbuf,
                 const _Float16* __restrict__ kbuf,
                 const _Float16* __restrict__ vt,
                 _Float16* __restrict__ ctx) {
    const int qt = blockIdx.x;
    const int bh = blockIdx.y;
    const int b = bh >> 5, h = bh & 31;
    const int tid = threadIdx.x;
    const int w = tid >> 6, lane = tid & 63;
    const int col = lane & 15, quad = lane >> 4;

    __shared__ _Float16 sK[128 * 128];   // K tile, reused for P
    __shared__ _Float16 sV[128 * 128];   // [d][s]

    half8 qf[2][4];
    const _Float16 qscale = (_Float16)0.08838834764831845f;  // 1/sqrt(128)
#pragma unroll
    for (int mt = 0; mt < 2; ++mt)
#pragma unroll
        for (int kc = 0; kc < 4; ++kc) {
            int row = qt * 128 + w * 32 + mt * 16 + col;
            half8 v = *(const half8*)&qbuf[((size_t)bh * SEQ + row) * DHEAD + kc * 32 + quad * 8];
            qf[mt][kc] = v * qscale;
        }

    float mrow[2][4], lrow[2][4];
    v4f o[2][8];
#pragma unroll
    for (int mt = 0; mt < 2; ++mt)
#pragma unroll
        for (int r = 0; r < 4; ++r) { mrow[mt][r] = -3.0e38f; lrow[mt][r] = 0.f; }
#pragma unroll
    for (int i = 0; i < 2; ++i)
#pragma unroll
        for (int j = 0; j < 8; ++j) { v4f z = {0.f, 0.f, 0.f, 0.f}; o[i][j] = z; }

    for (int kt = 0; kt <= qt; ++kt) {
        __syncthreads();
        {
            const _Float16* kg = kbuf + ((size_t)bh * SEQ + kt * 128) * DHEAD;
            const _Float16* vg = vt + (size_t)bh * DHEAD * SEQ + kt * 128;
#pragma unroll
            for (int i = 0; i < 8; ++i) {
                int rb = w * 32 + i * 4;
                gload_lds16(kg + (size_t)(rb + quad) * DHEAD + col * 8, &sK[rb * DHEAD]);
                gload_lds16(vg + (size_t)(rb + quad) * SEQ + col * 8, &sV[rb * 128]);
            }
        }
        __syncthreads();

        v4f sc[2][8];
#pragma unroll
        for (int i = 0; i < 2; ++i)
#pragma unroll
            for (int j = 0; j < 8; ++j) { v4f z = {0.f, 0.f, 0.f, 0.f}; sc[i][j] = z; }
#pragma unroll
        for (int kc = 0; kc < 4; ++kc)
#pragma unroll
            for (int nt = 0; nt < 8; ++nt) {
                half8 bf = *(const half8*)&sK[(size_t)(nt * 16 + col) * DHEAD + kc * 32 + quad * 8];
                sc[0][nt] = mfma16(qf[0][kc], bf, sc[0][nt]);
                sc[1][nt] = mfma16(qf[1][kc], bf, sc[1][nt]);
            }

        if (kt == qt) {
#pragma unroll
            for (int mt = 0; mt < 2; ++mt)
#pragma unroll
                for (int nt = 0; nt < 8; ++nt)
#pragma unroll
                    for (int r = 0; r < 4; ++r) {
                        int rowa = w * 32 + mt * 16 + quad * 4 + r;
                        int cola = nt * 16 + col;
                        if (cola > rowa) sc[mt][nt][r] = -3.0e38f;
                    }
        }

#pragma unroll
        for (int mt = 0; mt < 2; ++mt)
#pragma unroll
            for (int r = 0; r < 4; ++r) {
                float mx = sc[mt][0][r];
#pragma unroll
                for (int nt = 1; nt < 8; ++nt) mx = fmaxf(mx, sc[mt][nt][r]);
                mx = fmaxf(mx, __shfl_xor(mx, 1));
                mx = fmaxf(mx, __shfl_xor(mx, 2));
                mx = fmaxf(mx, __shfl_xor(mx, 4));
                mx = fmaxf(mx, __shfl_xor(mx, 8));
                float newm = fmaxf(mrow[mt][r], mx);
                float alpha = __expf(mrow[mt][r] - newm);
                mrow[mt][r] = newm;
                float rs = 0.f;
#pragma unroll
                for (int nt = 0; nt < 8; ++nt) {
                    float p = __expf(sc[mt][nt][r] - newm);
                    sc[mt][nt][r] = p;
                    rs += p;
                }
                rs += __shfl_xor(rs, 1); rs += __shfl_xor(rs, 2);
                rs += __shfl_xor(rs, 4); rs += __shfl_xor(rs, 8);
                lrow[mt][r] = lrow[mt][r] * alpha + rs;
#pragma unroll
                for (int nt = 0; nt < 8; ++nt) o[mt][nt][r] *= alpha;
            }

        __syncthreads();  // everyone done reading K frags
#pragma unroll
        for (int mt = 0; mt < 2; ++mt)
#pragma unroll
            for (int nt = 0; nt < 8; ++nt)
#pragma unroll
                for (int r = 0; r < 4; ++r)
                    sK[(size_t)(w * 32 + mt * 16 + quad * 4 + r) * 128 + nt * 16 + col] =
                        (_Float16)sc[mt][nt][r];
        __syncthreads();

#pragma unroll
        for (int kc = 0; kc < 4; ++kc) {
            half8 p0 = *(const half8*)&sK[(size_t)(w * 32 + col) * 128 + kc * 32 + quad * 8];
            half8 p1 = *(const half8*)&sK[(size_t)(w * 32 + 16 + col) * 128 + kc * 32 + quad * 8];
#pragma unroll
            for (int nt = 0; nt < 8; ++nt) {
                half8 vf = *(const half8*)&sV[(size_t)(nt * 16 + col) * 128 + kc * 32 + quad * 8];
                o[0][nt] = mfma16(p0, vf, o[0][nt]);
                o[1][nt] = mfma16(p1, vf, o[1][nt]);
            }
        }
    }

#pragma unroll
    for (int mt = 0; mt < 2; ++mt)
#pragma unroll
        for (int r = 0; r < 4; ++r) {
            int rowa = qt * 128 + w * 32 + mt * 16 + quad * 4 + r;
            float inv = 1.0f / lrow[mt][r];
            _Float16* dst = ctx + ((size_t)b * SEQ + rowa) * HID + h * DHEAD;
#pragma unroll
            for (int nt = 0; nt < 8; ++nt)
                dst[nt * 16 + col] = (_Float16)(o[mt][nt][r] * inv);
        }
}

extern "C" void kernel_launch(void* const* d_in, const int* in_sizes, int n_in,
                              void* d_out, int out_size, void* d_ws, size_t ws_size,
                              hipStream_t stream) {
    const float* hidden = (const float*)d_in[0];
    const int*   tt     = (const int*)d_in[1];
    const int*   pos    = (const int*)d_in[2];
    const float* wvq    = (const float*)d_in[3];
    const float* wlq    = (const float*)d_in[4];
    const float* wvd    = (const float*)d_in[5];
    const float* wld    = (const float*)d_in[6];
    float* out = (float*)d_out;

    char* ws = (char*)d_ws;
    size_t off = 0;
    auto alloc = [&](size_t bytes) {
        char* p = ws + off;
        off += (bytes + 255) & ~(size_t)255;
        return p;
    };
    const size_t TOKB = (size_t)T_TOKENS * HID * sizeof(_Float16);  // 33.5 MB
    _Float16* h16  = (_Float16*)alloc(TOKB);                        // later reused as vT
    _Float16* wvqT = (_Float16*)alloc((size_t)NQKV * HID * 2);
    _Float16* wlqT = (_Float16*)alloc((size_t)NQKV * HID * 2);
    _Float16* wvdT = (_Float16*)alloc((size_t)HID * HID * 2);
    _Float16* wldT = (_Float16*)alloc((size_t)HID * HID * 2);
    _Float16* qb   = (_Float16*)alloc(TOKB);
    _Float16* kb   = (_Float16*)alloc(TOKB);
    _Float16* vtmp = (_Float16*)alloc(TOKB);                        // later reused as ctx
    int* counts = (int*)alloc(2 * sizeof(int));
    int* idx    = (int*)alloc(2 * T_TOKENS * sizeof(int));
    float2* rope = (float2*)alloc((size_t)T_TOKENS * 64 * sizeof(float2));
    _Float16* vT  = h16;    // hidden16 dead after QKV GEMM
    _Float16* ctx = vtmp;   // v token-major dead after transpose_v

    hipMemsetAsync(counts, 0, 2 * sizeof(int), stream);
    route_kernel<<<T_TOKENS / 256, 256, 0, stream>>>(tt, counts, idx);
    rope_table_kernel<<<(T_TOKENS * 64) / 256, 256, 0, stream>>>(pos, rope);
    cvt_f32_f16<<<(T_TOKENS * HID / 4) / 256, 256, 0, stream>>>(hidden, h16, T_TOKENS * HID / 4);
    transpose_cvt<<<dim3(NQKV / 64, HID / 64), 256, 0, stream>>>(wvq, wvqT, HID, NQKV);
    transpose_cvt<<<dim3(NQKV / 64, HID / 64), 256, 0, stream>>>(wlq, wlqT, HID, NQKV);
    transpose_cvt<<<dim3(HID / 64, HID / 64), 256, 0, stream>>>(wvd, wvdT, HID, HID);
    transpose_cvt<<<dim3(HID / 64, HID / 64), 256, 0, stream>>>(wld, wldT, HID, HID);
    gemm_expert<0><<<dim3(NQKV / 128, T_TOKENS / 128, 2), 256, 0, stream>>>(
        h16, wvqT, wlqT, counts, idx, rope, qb, kb, vtmp, nullptr);
    transpose_v<<<dim3(SEQ / 64, DHEAD / 64, NB * NHEADS), 256, 0, stream>>>(vtmp, vT);
    attn_kernel<<<dim3(SEQ / 128, NB * NHEADS), 256, 0, stream>>>(qb, kb, vT, ctx);
    gemm_expert<1><<<dim3(HID / 128, T_TOKENS / 128, 2), 256, 0, stream>>>(
        ctx, wvdT, wldT, counts, idx, nullptr, nullptr, nullptr, nullptr, out);
}